// Round 4
// baseline (178.206 us; speedup 1.0000x reference)
//
#include <hip/hip_runtime.h>

// DMS_STAttention reduces algebraically to a broadcast:
//   H=1 => softmax over head axis == 1.0 everywhere, so
//   sa = 1 + sa_bias (broadcast over B), ta = 1 + ta_bias (broadcast over B).
// src and all weight inputs are dead code.
//
// Pure write kernel: 57.7 MB out, ~28 KB bias reads (L1/L2 resident).
// Flat grid, one float4 per thread, nontemporal stores (output never re-read).

typedef float f32x4 __attribute__((ext_vector_type(4)));  // native vec for nontemporal builtin

constexpr int B = 2048, T = 10, J = 22;
constexpr int SA_ELEMS = B * T * J * J;   // 9,912,320
constexpr int TA_ELEMS = B * J * T * T;   // 4,505,600
constexpr int SA_P4 = (T * J * J) / 4;    // 1210  (float4 period, sa)
constexpr int TA_P4 = (J * T * T) / 4;    // 550   (float4 period, ta)
constexpr int SA_F4 = SA_ELEMS / 4;       // 2,478,080
constexpr int TOT_F4 = (SA_ELEMS + TA_ELEMS) / 4;  // 3,604,480 = 14080 * 256

__global__ void __launch_bounds__(256)
bias_broadcast_kernel(const f32x4* __restrict__ sa_bias4,
                      const f32x4* __restrict__ ta_bias4,
                      f32x4* __restrict__ out4) {
    int v = blockIdx.x * 256 + threadIdx.x;
    if (v >= TOT_F4) return;
    f32x4 b;
    if (v < SA_F4) {
        b = sa_bias4[v % SA_P4];          // constexpr divisor -> magic-mul, cheap
    } else {
        b = ta_bias4[(v - SA_F4) % TA_P4];
    }
    b += 1.0f;
    __builtin_nontemporal_store(b, &out4[v]);
}

extern "C" void kernel_launch(void* const* d_in, const int* in_sizes, int n_in,
                              void* d_out, int out_size, void* d_ws, size_t ws_size,
                              hipStream_t stream) {
    // Inputs (setup_inputs dict order): 11: sa_bias [T,J,J], 12: ta_bias [J,T,T]
    const f32x4* sa_bias4 = (const f32x4*)d_in[11];
    const f32x4* ta_bias4 = (const f32x4*)d_in[12];
    f32x4* out4 = (f32x4*)d_out;

    int grid = TOT_F4 / 256;  // 14080 exactly, no remainder
    bias_broadcast_kernel<<<grid, 256, 0, stream>>>(sa_bias4, ta_bias4, out4);
}